// Round 6
// baseline (3053.808 us; speedup 1.0000x reference)
//
#include <hip/hip_runtime.h>

#define NPTS 8192
#define NB 4
#define NCH 128
#define DQK 48
#define TK 64
#define SH2 28.853901f            // 20 * log2(e)
#define LOG2E 1.4426950408889634f

typedef unsigned short ushort_t;
typedef unsigned int uint_t;
typedef __attribute__((ext_vector_type(8))) short bf16x8;
typedef __attribute__((ext_vector_type(4))) float f32x4;
typedef __attribute__((ext_vector_type(16))) float f32x16;

static __device__ __forceinline__ ushort_t f2bf(float x) {
  union { float f; uint_t u; } v; v.f = x;
  uint_t r = v.u + 0x7fffu + ((v.u >> 16) & 1u);
  return (ushort_t)(r >> 16);
}
static __device__ __forceinline__ float bf2f(ushort_t u) {
  union { uint_t i; float f; } v; v.i = ((uint_t)u) << 16; return v.f;
}

typedef __attribute__((address_space(1))) void void_g;
typedef __attribute__((address_space(3))) void void_l;
static __device__ __forceinline__ void gload_lds16(const ushort_t* g, ushort_t* l) {
  __builtin_amdgcn_global_load_lds((void_g*)(ushort_t*)g, (void_l*)l, 16, 0, 0);
}

// ---------------------------------------------------------------------------
// Projections, 2 points/thread (halves LDS broadcast instrs per output).
// z=0: Q rows [n][48] = {q*log2e (32), sqrt(.1)*log2e*xhat (3), 0}; z=1: K
// rows (unscaled); z=2..5: V 32-ch chunks -> Vt[b][ch][n] bf16.
// ---------------------------------------------------------------------------
__global__ __launch_bounds__(256, 4)
void proj5_kernel(const float* __restrict__ x, const float* __restrict__ xyz,
                  const float* __restrict__ Wq, const float* __restrict__ bq,
                  const float* __restrict__ Wk, const float* __restrict__ bk,
                  const float* __restrict__ Wv, const float* __restrict__ bv,
                  ushort_t* __restrict__ Qb, ushort_t* __restrict__ Kb,
                  ushort_t* __restrict__ Vt) {
  __shared__ float wt[128 * 36];  // wt[c*36 + r], r<32 (broadcast reads)
  const int tid = threadIdx.x;
  const int b = blockIdx.y, z = blockIdx.z;
  const int n0 = blockIdx.x * 512 + tid;  // second point: n0 + 256

  const float* W; const float* bias; int c0 = 0;
  if (z == 0)      { W = Wq; bias = bq; }
  else if (z == 1) { W = Wk; bias = bk; }
  else { c0 = (z - 2) * 32; W = Wv + (size_t)c0 * 128; bias = bv + c0; }

  for (int idx = tid; idx < 32 * 128; idx += 256) {
    int r = idx >> 7, c = idx & 127;
    wt[c * 36 + r] = W[idx];
  }
  __syncthreads();

  float acc0[32], acc1[32];
#pragma unroll
  for (int j = 0; j < 32; ++j) { acc0[j] = bias[j]; acc1[j] = acc0[j]; }

  const float* xb = x + (size_t)b * NCH * NPTS;
#pragma unroll 2
  for (int c = 0; c < 128; ++c) {
    float xv0 = xb[(size_t)c * NPTS + n0];
    float xv1 = xb[(size_t)c * NPTS + n0 + 256];
    const float4* w4 = (const float4*)&wt[c * 36];
#pragma unroll
    for (int j4 = 0; j4 < 8; ++j4) {
      float4 w = w4[j4];
      acc0[j4 * 4 + 0] = fmaf(w.x, xv0, acc0[j4 * 4 + 0]);
      acc0[j4 * 4 + 1] = fmaf(w.y, xv0, acc0[j4 * 4 + 1]);
      acc0[j4 * 4 + 2] = fmaf(w.z, xv0, acc0[j4 * 4 + 2]);
      acc0[j4 * 4 + 3] = fmaf(w.w, xv0, acc0[j4 * 4 + 3]);
      acc1[j4 * 4 + 0] = fmaf(w.x, xv1, acc1[j4 * 4 + 0]);
      acc1[j4 * 4 + 1] = fmaf(w.y, xv1, acc1[j4 * 4 + 1]);
      acc1[j4 * 4 + 2] = fmaf(w.z, xv1, acc1[j4 * 4 + 2]);
      acc1[j4 * 4 + 3] = fmaf(w.w, xv1, acc1[j4 * 4 + 3]);
    }
  }

#pragma unroll
  for (int u = 0; u < 2; ++u) {
    const float* acc = u ? acc1 : acc0;
    const int n = n0 + u * 256;
    if (z <= 1) {
      const float sc = (z == 0) ? LOG2E : 1.0f;
      float xa = xyz[((size_t)b * NPTS + n) * 3 + 0];
      float xc = xyz[((size_t)b * NPTS + n) * 3 + 1];
      float xd = xyz[((size_t)b * NPTS + n) * 3 + 2];
      float rn = 0.31622776601683794f * sc /
                 (sqrtf(xa * xa + xc * xc + xd * xd) + 1e-8f);
      ushort_t row[48];
#pragma unroll
      for (int j = 0; j < 32; ++j) row[j] = f2bf(acc[j] * sc);
      row[32] = f2bf(xa * rn); row[33] = f2bf(xc * rn); row[34] = f2bf(xd * rn);
#pragma unroll
      for (int j = 35; j < 48; ++j) row[j] = 0;
      ushort_t* dst = (z == 0 ? Qb : Kb) + ((size_t)b * NPTS + n) * DQK;
#pragma unroll
      for (int j = 0; j < 6; ++j)
        *(bf16x8*)(dst + j * 8) = *(const bf16x8*)(row + j * 8);
    } else {
#pragma unroll
      for (int j = 0; j < 32; ++j)
        Vt[((size_t)b * NCH + c0 + j) * NPTS + n] = f2bf(acc[j]);
    }
  }
}

// ---------------------------------------------------------------------------
// MFMA flash attention, 32x32x16, 64 q/wave, 8 waves = 512 q/block.
// SPL key-split segments; 2 blocks/CU at SPL=8 -> 4 waves/SIMD.
// Double-buffered global_load_lds staging, one barrier per round.
// exp2-domain constant-shift softmax; shift folded into MFMA C-init.
// ---------------------------------------------------------------------------
template <int SPL>
__global__ __launch_bounds__(512, 4)
void attn32_kernel(const ushort_t* __restrict__ Qb, const ushort_t* __restrict__ Kb,
                   const ushort_t* __restrict__ Vt,
                   ushort_t* __restrict__ PACC, float* __restrict__ PL) {
  // frag f: K = kb*3+c (6), V = 6 + fch*4 + kk (16); each 64 lanes x 16B
  __shared__ __align__(16) ushort_t L[2][22][512];
  const int tid = threadIdx.x;
  const int lane = tid & 63, w = tid >> 6;
  const int l31 = lane & 31, h = lane >> 5;

  const int lin = blockIdx.x;
  const int nbs = 4 * SPL;
  const int bs = lin & (nbs - 1);   // XCD = lin&7 -> few (b,seg) combos per XCD
  const int b = bs & 3, sseg = bs >> 2;
  const int qblk = lin / nbs;       // 0..15
  const int q0w = qblk * 512 + w * 64;
  const int m00 = sseg * (NPTS / SPL);
  const int rounds = (NPTS / SPL) / TK;

  // persistent Q^T B-frags: q = q0w + g*32 + l31, d = c*16 + h*8 + j
  bf16x8 qf[2][3];
#pragma unroll
  for (int g = 0; g < 2; ++g)
#pragma unroll
    for (int c = 0; c < 3; ++c)
      qf[g][c] = *(const bf16x8*)(Qb + ((size_t)b * NPTS + q0w + g * 32 + l31) * DQK +
                                  c * 16 + h * 8);

  // staging: wave w handles frags {w, w+8, w+16} (22 total)
  const ushort_t* gp[3];
  int fid[3], adv[3];
  const int nf = (w < 6) ? 3 : 2;
  for (int i = 0; i < nf; ++i) {
    int fi = w + 8 * i;
    fid[i] = fi;
    if (fi < 6) {
      int kb = fi / 3, c = fi - kb * 3;
      gp[i] = Kb + ((size_t)b * NPTS + m00 + kb * 32 + l31) * DQK + c * 16 + h * 8;
      adv[i] = TK * DQK;
    } else {
      int vi = fi - 6, fch = vi >> 2, kk = vi & 3;
      gp[i] = Vt + ((size_t)b * NCH + fch * 32 + l31) * NPTS + m00 + kk * 16 + h * 8;
      adv[i] = TK;
    }
  }

  f32x16 O[2][4];
#pragma unroll
  for (int g = 0; g < 2; ++g)
#pragma unroll
    for (int f = 0; f < 4; ++f) O[g][f] = (f32x16)(0.f);
  float lsum0 = 0.f, lsum1 = 0.f;
  const f32x16 cinit = (f32x16)(-SH2);  // S starts at -shift (exp2 domain)

  // prologue: stage round 0 into buffer 0
  for (int i = 0; i < nf; ++i) gload_lds16(gp[i], &L[0][fid[i]][0]);

#pragma unroll 1
  for (int t = 0; t < rounds; ++t) {
    __syncthreads();  // auto vmcnt(0): buf[t&1] DMA drained; all waves synced
    const int cur = t & 1;
    if (t + 1 < rounds) {
      for (int i = 0; i < nf; ++i) {
        gp[i] += adv[i];
        gload_lds16(gp[i], &L[cur ^ 1][fid[i]][0]);  // overlaps compute below
      }
    }

#pragma unroll
    for (int kb = 0; kb < 2; ++kb) {
      bf16x8 kf0 = *(const bf16x8*)(&L[cur][kb * 3 + 0][0] + lane * 8);
      bf16x8 kf1 = *(const bf16x8*)(&L[cur][kb * 3 + 1][0] + lane * 8);
      bf16x8 kf2 = *(const bf16x8*)(&L[cur][kb * 3 + 2][0] + lane * 8);

      uint_t pk[2][8];
#pragma unroll
      for (int g = 0; g < 2; ++g) {
        f32x16 S = __builtin_amdgcn_mfma_f32_32x32x16_bf16(kf0, qf[g][0], cinit, 0, 0, 0);
        S = __builtin_amdgcn_mfma_f32_32x32x16_bf16(kf1, qf[g][1], S, 0, 0, 0);
        S = __builtin_amdgcn_mfma_f32_32x32x16_bf16(kf2, qf[g][2], S, 0, 0, 0);
        float p[16];
        float ts = 0.f;
#pragma unroll
        for (int r = 0; r < 16; ++r) {
          p[r] = __builtin_amdgcn_exp2f(S[r]);
          ts += p[r];
        }
        if (g == 0) lsum0 += ts; else lsum1 += ts;
#pragma unroll
        for (int i = 0; i < 8; ++i)
          pk[g][i] = __builtin_amdgcn_perm(__float_as_uint(p[2 * i + 1]),
                                           __float_as_uint(p[2 * i]), 0x07060302u);
      }

      // cross-half exchange for C->A transpose
      uint_t X[2][8];
#pragma unroll
      for (int g = 0; g < 2; ++g)
#pragma unroll
        for (int i = 0; i < 8; ++i) X[g][i] = (uint_t)__shfl_xor((int)pk[g][i], 32);

#pragma unroll
      for (int kkl = 0; kkl < 2; ++kkl) {
        bf16x8 A[2];
#pragma unroll
        for (int g = 0; g < 2; ++g) {
          union { uint_t u[4]; bf16x8 v; } au;
          au.u[0] = h ? X[g][4 * kkl + 2] : pk[g][4 * kkl + 0];
          au.u[1] = h ? X[g][4 * kkl + 3] : pk[g][4 * kkl + 1];
          au.u[2] = h ? pk[g][4 * kkl + 2] : X[g][4 * kkl + 0];
          au.u[3] = h ? pk[g][4 * kkl + 3] : X[g][4 * kkl + 1];
          A[g] = au.v;
        }
#pragma unroll
        for (int f = 0; f < 4; ++f) {
          bf16x8 vf = *(const bf16x8*)(&L[cur][6 + f * 4 + kb * 2 + kkl][0] + lane * 8);
          O[0][f] = __builtin_amdgcn_mfma_f32_32x32x16_bf16(A[0], vf, O[0][f], 0, 0, 0);
          O[1][f] = __builtin_amdgcn_mfma_f32_32x32x16_bf16(A[1], vf, O[1][f], 0, 0, 0);
        }
      }
    }
  }

  // epilogue
  lsum0 += __shfl_xor(lsum0, 32);
  lsum1 += __shfl_xor(lsum1, 32);
  const size_t pbase = (((size_t)bs * 16 + qblk) * 8 + w) * 2;
#pragma unroll
  for (int g = 0; g < 2; ++g) {
#pragma unroll
    for (int f = 0; f < 4; ++f) {
      union { ushort_t u[16]; bf16x8 v[2]; } pu;
#pragma unroll
      for (int r = 0; r < 16; ++r) pu.u[r] = f2bf(O[g][f][r]);
      size_t idx = ((pbase + g) * 4 + f) * 1024 + (size_t)lane * 16;
      *(bf16x8*)(PACC + idx) = pu.v[0];
      *(bf16x8*)(PACC + idx + 8) = pu.v[1];
    }
    if (lane < 32)
      PL[(size_t)bs * NPTS + q0w + g * 32 + lane] = (g == 0) ? lsum0 : lsum1;
  }
}

// ---------------------------------------------------------------------------
// Merge SPL key-split partials (linear) + gamma + x.
// grid (qblk2 32, b 4, f 4); each block: 256 q x 32 ch.
// ---------------------------------------------------------------------------
template <int SPL>
__global__ __launch_bounds__(256, 4)
void merge_kernel(const ushort_t* __restrict__ PACC, const float* __restrict__ PL,
                  const float* __restrict__ x, const float* __restrict__ gamma,
                  float* __restrict__ out) {
  __shared__ float Linv[256];
  const int tid = threadIdx.x;
  const int qblk2 = blockIdx.x, b = blockIdx.y, f = blockIdx.z;
  const int q0 = qblk2 * 256;

  float Ls = 0.f;
#pragma unroll
  for (int s = 0; s < SPL; ++s)
    Ls += PL[(size_t)(s * 4 + b) * NPTS + q0 + tid];
  Linv[tid] = gamma[0] / Ls;
  __syncthreads();

  const int ww = tid >> 6, lane = tid & 63, l31 = lane & 31, h = lane >> 5;
  const int ch = f * 32 + l31;
  const float* xrow = x + ((size_t)b * NCH + ch) * NPTS + q0;
  float* orow = out + ((size_t)b * NCH + ch) * NPTS + q0;

#pragma unroll
  for (int g = 0; g < 2; ++g) {
    float acc[16];
#pragma unroll
    for (int r = 0; r < 16; ++r) acc[r] = 0.f;
#pragma unroll
    for (int s = 0; s < SPL; ++s) {
      size_t idx = (((((size_t)(s * 4 + b) * 16 + (qblk2 >> 1)) * 8 +
                      (qblk2 & 1) * 4 + ww) * 2 + g) * 4 + f) * 1024 +
                   (size_t)lane * 16;
      bf16x8 a0 = *(const bf16x8*)(PACC + idx);
      bf16x8 a1 = *(const bf16x8*)(PACC + idx + 8);
#pragma unroll
      for (int r = 0; r < 8; ++r) {
        acc[r] += bf2f((ushort_t)a0[r]);
        acc[8 + r] += bf2f((ushort_t)a1[r]);
      }
    }
    const int qb = ww * 64 + g * 32;
#pragma unroll
    for (int rr = 0; rr < 4; ++rr) {
      int q = qb + 8 * rr + 4 * h;
      f32x4 xv = *(const f32x4*)(xrow + q);
      f32x4 o;
#pragma unroll
      for (int i = 0; i < 4; ++i) o[i] = acc[rr * 4 + i] * Linv[q + i] + xv[i];
      *(f32x4*)(orow + q) = o;
    }
  }
}

// ---------------------------------------------------------------------------
extern "C" void kernel_launch(void* const* d_in, const int* in_sizes, int n_in,
                              void* d_out, int out_size, void* d_ws,
                              size_t ws_size, hipStream_t stream) {
  const float* x     = (const float*)d_in[0];
  const float* xyz   = (const float*)d_in[1];
  const float* Wq    = (const float*)d_in[2];
  const float* bq    = (const float*)d_in[3];
  const float* Wk    = (const float*)d_in[4];
  const float* bk    = (const float*)d_in[5];
  const float* Wv    = (const float*)d_in[6];
  const float* bv    = (const float*)d_in[7];
  const float* gamma = (const float*)d_in[8];
  float* out = (float*)d_out;

  const size_t BN = (size_t)NB * NPTS;
  ushort_t* Qb = (ushort_t*)d_ws;
  ushort_t* Kb = Qb + BN * DQK;
  ushort_t* Vt = Kb + BN * DQK;
  ushort_t* PACC = Vt + BN * NCH;
  const size_t base_bytes = (char*)(PACC)-(char*)d_ws;
  const size_t need8 = base_bytes + 8 * BN * NCH * 2 + 8 * BN * 4;

  proj5_kernel<<<dim3(NPTS / 512, NB, 6), 256, 0, stream>>>(
      x, xyz, Wq, bq, Wk, bk, Wv, bv, Qb, Kb, Vt);

  if (ws_size >= need8) {
    float* PL = (float*)(PACC + (size_t)8 * BN * NCH);
    attn32_kernel<8><<<512, 512, 0, stream>>>(Qb, Kb, Vt, PACC, PL);
    merge_kernel<8><<<dim3(32, NB, 4), 256, 0, stream>>>(PACC, PL, x, gamma, out);
  } else {
    float* PL = (float*)(PACC + (size_t)4 * BN * NCH);
    attn32_kernel<4><<<256, 512, 0, stream>>>(Qb, Kb, Vt, PACC, PL);
    merge_kernel<4><<<dim3(32, NB, 4), 256, 0, stream>>>(PACC, PL, x, gamma, out);
  }
  (void)in_sizes; (void)n_in; (void)out_size;
}

// Round 7
// 282.352 us; speedup vs baseline: 10.8156x; 10.8156x over previous
//
#include <hip/hip_runtime.h>

#define NPTS 8192
#define NB 4
#define NCH 128
#define DQK 48
#define TK 64
#define SPLIT 4
#define KEYS_PER (NPTS / SPLIT)   // 2048
#define ROUNDS (KEYS_PER / TK)    // 32
#define SH2 28.853901f            // 20 * log2(e)
#define LOG2E 1.4426950408889634f

typedef unsigned short ushort_t;
typedef unsigned int uint_t;
typedef __attribute__((ext_vector_type(8))) short bf16x8;
typedef __attribute__((ext_vector_type(4))) float f32x4;
typedef __attribute__((ext_vector_type(16))) float f32x16;

static __device__ __forceinline__ ushort_t f2bf(float x) {
  union { float f; uint_t u; } v; v.f = x;
  uint_t r = v.u + 0x7fffu + ((v.u >> 16) & 1u);
  return (ushort_t)(r >> 16);
}
static __device__ __forceinline__ float bf2f(ushort_t u) {
  union { uint_t i; float f; } v; v.i = ((uint_t)u) << 16; return v.f;
}
// sigma16: swap middle two 4-blocks of each 16-group (involution).
// Makes S^T C-layout regs directly usable as the PV A-fragment.
static __device__ __forceinline__ int sig16(int n) {
  int g2 = (n >> 2) & 3;
  return (g2 == 1 || g2 == 2) ? (n ^ 0xC) : n;
}

typedef __attribute__((address_space(1))) void void_g;
typedef __attribute__((address_space(3))) void void_l;
static __device__ __forceinline__ void gload_lds16(const ushort_t* g, ushort_t* l) {
  __builtin_amdgcn_global_load_lds((void_g*)(ushort_t*)g, (void_l*)l, 16, 0, 0);
}

// ---------------------------------------------------------------------------
// Projections, 2 points/thread. z=0: Q rows [n][48] = {q*log2e, sqrt(.1)*
// log2e*xhat, 0}; z=1: K rows; z=2..5: V -> Vt[b][ch][sig16-permuted n] bf16.
// ---------------------------------------------------------------------------
__global__ __launch_bounds__(256, 4)
void proj5_kernel(const float* __restrict__ x, const float* __restrict__ xyz,
                  const float* __restrict__ Wq, const float* __restrict__ bq,
                  const float* __restrict__ Wk, const float* __restrict__ bk,
                  const float* __restrict__ Wv, const float* __restrict__ bv,
                  ushort_t* __restrict__ Qb, ushort_t* __restrict__ Kb,
                  ushort_t* __restrict__ Vt) {
  __shared__ float wt[128 * 36];  // wt[c*36 + r], r<32 (broadcast reads)
  const int tid = threadIdx.x;
  const int b = blockIdx.y, z = blockIdx.z;
  const int n0 = blockIdx.x * 512 + tid;  // second point: n0 + 256

  const float* W; const float* bias; int c0 = 0;
  if (z == 0)      { W = Wq; bias = bq; }
  else if (z == 1) { W = Wk; bias = bk; }
  else { c0 = (z - 2) * 32; W = Wv + (size_t)c0 * 128; bias = bv + c0; }

  for (int idx = tid; idx < 32 * 128; idx += 256) {
    int r = idx >> 7, c = idx & 127;
    wt[c * 36 + r] = W[idx];
  }
  __syncthreads();

  float acc0[32], acc1[32];
#pragma unroll
  for (int j = 0; j < 32; ++j) { acc0[j] = bias[j]; acc1[j] = acc0[j]; }

  const float* xb = x + (size_t)b * NCH * NPTS;
#pragma unroll 2
  for (int c = 0; c < 128; ++c) {
    float xv0 = xb[(size_t)c * NPTS + n0];
    float xv1 = xb[(size_t)c * NPTS + n0 + 256];
    const float4* w4 = (const float4*)&wt[c * 36];
#pragma unroll
    for (int j4 = 0; j4 < 8; ++j4) {
      float4 w = w4[j4];
      acc0[j4 * 4 + 0] = fmaf(w.x, xv0, acc0[j4 * 4 + 0]);
      acc0[j4 * 4 + 1] = fmaf(w.y, xv0, acc0[j4 * 4 + 1]);
      acc0[j4 * 4 + 2] = fmaf(w.z, xv0, acc0[j4 * 4 + 2]);
      acc0[j4 * 4 + 3] = fmaf(w.w, xv0, acc0[j4 * 4 + 3]);
      acc1[j4 * 4 + 0] = fmaf(w.x, xv1, acc1[j4 * 4 + 0]);
      acc1[j4 * 4 + 1] = fmaf(w.y, xv1, acc1[j4 * 4 + 1]);
      acc1[j4 * 4 + 2] = fmaf(w.z, xv1, acc1[j4 * 4 + 2]);
      acc1[j4 * 4 + 3] = fmaf(w.w, xv1, acc1[j4 * 4 + 3]);
    }
  }

#pragma unroll
  for (int u = 0; u < 2; ++u) {
    const float* acc = u ? acc1 : acc0;
    const int n = n0 + u * 256;
    if (z <= 1) {
      const float sc = (z == 0) ? LOG2E : 1.0f;
      float xa = xyz[((size_t)b * NPTS + n) * 3 + 0];
      float xc = xyz[((size_t)b * NPTS + n) * 3 + 1];
      float xd = xyz[((size_t)b * NPTS + n) * 3 + 2];
      float rn = 0.31622776601683794f * sc /
                 (sqrtf(xa * xa + xc * xc + xd * xd) + 1e-8f);
      ushort_t row[48];
#pragma unroll
      for (int j = 0; j < 32; ++j) row[j] = f2bf(acc[j] * sc);
      row[32] = f2bf(xa * rn); row[33] = f2bf(xc * rn); row[34] = f2bf(xd * rn);
#pragma unroll
      for (int j = 35; j < 48; ++j) row[j] = 0;
      ushort_t* dst = (z == 0 ? Qb : Kb) + ((size_t)b * NPTS + n) * DQK;
#pragma unroll
      for (int j = 0; j < 6; ++j)
        *(bf16x8*)(dst + j * 8) = *(const bf16x8*)(row + j * 8);
    } else {
      const int np = (n & ~15) | sig16(n & 15);  // key-permuted V storage
#pragma unroll
      for (int j = 0; j < 32; ++j)
        Vt[((size_t)b * NCH + c0 + j) * NPTS + np] = f2bf(acc[j]);
    }
  }
}

// ---------------------------------------------------------------------------
// MFMA flash attention, 32x32x16, 64 q/wave, 8 waves = 512 q/block.
// Double-buffered global_load_lds staging, one barrier per round.
// exp2 constant-shift softmax folded into MFMA C-init. V is sigma16-permuted
// so the S^T C-regs pack DIRECTLY into the PV A-fragment (no shuffles).
// ---------------------------------------------------------------------------
__global__ __launch_bounds__(512, 2)
void attn32_kernel(const ushort_t* __restrict__ Qb, const ushort_t* __restrict__ Kb,
                   const ushort_t* __restrict__ Vt,
                   ushort_t* __restrict__ PACC, float* __restrict__ PL) {
  // frag f: K = kb*3+c (6), V = 6 + fch*4 + kk (16); each 64 lanes x 16B
  __shared__ __align__(16) ushort_t L[2][22][512];
  const int tid = threadIdx.x;
  const int lane = tid & 63, w = tid >> 6;
  const int l31 = lane & 31, h = lane >> 5;

  const int lin = blockIdx.x;
  const int bs = lin & 15;          // XCD x sees bs in {x, x+8}: 2 (b,seg) combos
  const int b = bs & 3, sseg = bs >> 2;
  const int qblk = lin >> 4;        // 0..15
  const int q0w = qblk * 512 + w * 64;
  const int m00 = sseg * KEYS_PER;

  // persistent Q^T B-frags: q = q0w + g*32 + l31, d = c*16 + h*8 + j
  bf16x8 qf[2][3];
#pragma unroll
  for (int g = 0; g < 2; ++g)
#pragma unroll
    for (int c = 0; c < 3; ++c)
      qf[g][c] = *(const bf16x8*)(Qb + ((size_t)b * NPTS + q0w + g * 32 + l31) * DQK +
                                  c * 16 + h * 8);

  // staging: wave w handles frags {w, w+8, w+16} (22 total)
  const ushort_t* gp[3];
  int fid[3], adv[3];
  const int nf = (w < 6) ? 3 : 2;
  for (int i = 0; i < nf; ++i) {
    int fi = w + 8 * i;
    fid[i] = fi;
    if (fi < 6) {
      int kb = fi / 3, c = fi - kb * 3;
      gp[i] = Kb + ((size_t)b * NPTS + m00 + kb * 32 + l31) * DQK + c * 16 + h * 8;
      adv[i] = TK * DQK;
    } else {
      int vi = fi - 6, fch = vi >> 2, kk = vi & 3;
      gp[i] = Vt + ((size_t)b * NCH + fch * 32 + l31) * NPTS + m00 + kk * 16 + h * 8;
      adv[i] = TK;
    }
  }

  f32x16 O[2][4];
#pragma unroll
  for (int g = 0; g < 2; ++g)
#pragma unroll
    for (int f = 0; f < 4; ++f) O[g][f] = (f32x16)(0.f);
  float lsum0 = 0.f, lsum1 = 0.f;
  const f32x16 cinit = (f32x16)(-SH2);  // S starts at -shift (exp2 domain)

  // prologue: stage round 0 into buffer 0
  for (int i = 0; i < nf; ++i) gload_lds16(gp[i], &L[0][fid[i]][0]);

#pragma unroll 1
  for (int t = 0; t < ROUNDS; ++t) {
    __syncthreads();  // auto vmcnt(0): buf[t&1] DMA drained; all waves synced
    const int cur = t & 1;
    if (t + 1 < ROUNDS) {
      for (int i = 0; i < nf; ++i) {
        gp[i] += adv[i];
        gload_lds16(gp[i], &L[cur ^ 1][fid[i]][0]);  // overlaps compute below
      }
    }

#pragma unroll
    for (int kb = 0; kb < 2; ++kb) {
      bf16x8 kf0 = *(const bf16x8*)(&L[cur][kb * 3 + 0][0] + lane * 8);
      bf16x8 kf1 = *(const bf16x8*)(&L[cur][kb * 3 + 1][0] + lane * 8);
      bf16x8 kf2 = *(const bf16x8*)(&L[cur][kb * 3 + 2][0] + lane * 8);

      uint_t pk[2][8];
#pragma unroll
      for (int g = 0; g < 2; ++g) {
        f32x16 S = __builtin_amdgcn_mfma_f32_32x32x16_bf16(kf0, qf[g][0], cinit, 0, 0, 0);
        S = __builtin_amdgcn_mfma_f32_32x32x16_bf16(kf1, qf[g][1], S, 0, 0, 0);
        S = __builtin_amdgcn_mfma_f32_32x32x16_bf16(kf2, qf[g][2], S, 0, 0, 0);
        float p[16];
        float ts = 0.f;
#pragma unroll
        for (int r = 0; r < 16; ++r) {
          p[r] = __builtin_amdgcn_exp2f(S[r]);
          ts += p[r];
        }
        if (g == 0) lsum0 += ts; else lsum1 += ts;
#pragma unroll
        for (int i = 0; i < 8; ++i)
          pk[g][i] = __builtin_amdgcn_perm(__float_as_uint(p[2 * i + 1]),
                                           __float_as_uint(p[2 * i]), 0x07060302u);
      }

      // sigma16-permuted V => C-regs pack directly into PV A-frags
#pragma unroll
      for (int kkl = 0; kkl < 2; ++kkl) {
        bf16x8 A[2];
#pragma unroll
        for (int g = 0; g < 2; ++g) {
          union { uint_t u[4]; bf16x8 v; } au;
          au.u[0] = pk[g][4 * kkl + 0];
          au.u[1] = pk[g][4 * kkl + 1];
          au.u[2] = pk[g][4 * kkl + 2];
          au.u[3] = pk[g][4 * kkl + 3];
          A[g] = au.v;
        }
#pragma unroll
        for (int f = 0; f < 4; ++f) {
          bf16x8 vf = *(const bf16x8*)(&L[cur][6 + f * 4 + kb * 2 + kkl][0] + lane * 8);
          O[0][f] = __builtin_amdgcn_mfma_f32_32x32x16_bf16(A[0], vf, O[0][f], 0, 0, 0);
          O[1][f] = __builtin_amdgcn_mfma_f32_32x32x16_bf16(A[1], vf, O[1][f], 0, 0, 0);
        }
      }
    }
  }

  // epilogue
  lsum0 += __shfl_xor(lsum0, 32);
  lsum1 += __shfl_xor(lsum1, 32);
  const size_t pbase = (((size_t)bs * 16 + qblk) * 8 + w) * 2;
#pragma unroll
  for (int g = 0; g < 2; ++g) {
#pragma unroll
    for (int f = 0; f < 4; ++f) {
      union { ushort_t u[16]; bf16x8 v[2]; } pu;
#pragma unroll
      for (int r = 0; r < 16; ++r) pu.u[r] = f2bf(O[g][f][r]);
      size_t idx = ((pbase + g) * 4 + f) * 1024 + (size_t)lane * 16;
      *(bf16x8*)(PACC + idx) = pu.v[0];
      *(bf16x8*)(PACC + idx + 8) = pu.v[1];
    }
    if (lane < 32)
      PL[(size_t)bs * NPTS + q0w + g * 32 + lane] = (g == 0) ? lsum0 : lsum1;
  }
}

// ---------------------------------------------------------------------------
// Merge 4 key-split partials (linear) + gamma + x.
// grid (qblk2 32, b 4, f 4); each block: 256 q x 32 ch.
// ---------------------------------------------------------------------------
__global__ __launch_bounds__(256, 4)
void merge4_kernel(const ushort_t* __restrict__ PACC, const float* __restrict__ PL,
                   const float* __restrict__ x, const float* __restrict__ gamma,
                   float* __restrict__ out) {
  __shared__ float Linv[256];
  const int tid = threadIdx.x;
  const int qblk2 = blockIdx.x, b = blockIdx.y, f = blockIdx.z;
  const int q0 = qblk2 * 256;

  float Ls = 0.f;
#pragma unroll
  for (int s = 0; s < 4; ++s)
    Ls += PL[(size_t)(s * 4 + b) * NPTS + q0 + tid];
  Linv[tid] = gamma[0] / Ls;
  __syncthreads();

  const int ww = tid >> 6, lane = tid & 63, l31 = lane & 31, h = lane >> 5;
  const int ch = f * 32 + l31;
  const float* xrow = x + ((size_t)b * NCH + ch) * NPTS + q0;
  float* orow = out + ((size_t)b * NCH + ch) * NPTS + q0;

#pragma unroll
  for (int g = 0; g < 2; ++g) {
    float acc[16];
#pragma unroll
    for (int r = 0; r < 16; ++r) acc[r] = 0.f;
#pragma unroll
    for (int s = 0; s < 4; ++s) {
      size_t idx = (((((size_t)(s * 4 + b) * 16 + (qblk2 >> 1)) * 8 +
                      (qblk2 & 1) * 4 + ww) * 2 + g) * 4 + f) * 1024 +
                   (size_t)lane * 16;
      bf16x8 a0 = *(const bf16x8*)(PACC + idx);
      bf16x8 a1 = *(const bf16x8*)(PACC + idx + 8);
#pragma unroll
      for (int r = 0; r < 8; ++r) {
        acc[r] += bf2f((ushort_t)a0[r]);
        acc[8 + r] += bf2f((ushort_t)a1[r]);
      }
    }
    const int qb = ww * 64 + g * 32;
#pragma unroll
    for (int rr = 0; rr < 4; ++rr) {
      int q = qb + 8 * rr + 4 * h;
      f32x4 xv = *(const f32x4*)(xrow + q);
      f32x4 o;
#pragma unroll
      for (int i = 0; i < 4; ++i) o[i] = acc[rr * 4 + i] * Linv[q + i] + xv[i];
      *(f32x4*)(orow + q) = o;
    }
  }
}

// ---------------------------------------------------------------------------
extern "C" void kernel_launch(void* const* d_in, const int* in_sizes, int n_in,
                              void* d_out, int out_size, void* d_ws,
                              size_t ws_size, hipStream_t stream) {
  const float* x     = (const float*)d_in[0];
  const float* xyz   = (const float*)d_in[1];
  const float* Wq    = (const float*)d_in[2];
  const float* bq    = (const float*)d_in[3];
  const float* Wk    = (const float*)d_in[4];
  const float* bk    = (const float*)d_in[5];
  const float* Wv    = (const float*)d_in[6];
  const float* bv    = (const float*)d_in[7];
  const float* gamma = (const float*)d_in[8];
  float* out = (float*)d_out;

  const size_t BN = (size_t)NB * NPTS;
  ushort_t* Qb = (ushort_t*)d_ws;
  ushort_t* Kb = Qb + BN * DQK;
  ushort_t* Vt = Kb + BN * DQK;
  ushort_t* PACC = Vt + BN * NCH;   // 16 bs * 16 qblk * 8 w * 2 g * 4 f * 1024
  float* PL = (float*)(PACC + (size_t)16 * 16 * 8 * 2 * 4 * 1024);

  proj5_kernel<<<dim3(NPTS / 512, NB, 6), 256, 0, stream>>>(
      x, xyz, Wq, bq, Wk, bk, Wv, bv, Qb, Kb, Vt);
  attn32_kernel<<<256, 512, 0, stream>>>(Qb, Kb, Vt, PACC, PL);
  merge4_kernel<<<dim3(32, NB, 4), 256, 0, stream>>>(PACC, PL, x, gamma, out);
  (void)in_sizes; (void)n_in; (void)out_size; (void)ws_size;
}

// Round 8
// 204.325 us; speedup vs baseline: 14.9459x; 1.3819x over previous
//
#include <hip/hip_runtime.h>

#define NPTS 8192
#define NB 4
#define NCH 128
#define DQK 48
#define TK 64
#define SPLIT 4
#define KEYS_PER (NPTS / SPLIT)   // 2048
#define ROUNDS (KEYS_PER / TK)    // 32
#define SH2 28.853901f            // 20 * log2(e)
#define LOG2E 1.4426950408889634f

typedef unsigned short ushort_t;
typedef unsigned int uint_t;
typedef __attribute__((ext_vector_type(8))) short bf16x8;
typedef __attribute__((ext_vector_type(4))) float f32x4;
typedef __attribute__((ext_vector_type(16))) float f32x16;

static __device__ __forceinline__ ushort_t f2bf(float x) {
  union { float f; uint_t u; } v; v.f = x;
  uint_t r = v.u + 0x7fffu + ((v.u >> 16) & 1u);
  return (ushort_t)(r >> 16);
}
static __device__ __forceinline__ float bf2f(ushort_t u) {
  union { uint_t i; float f; } v; v.i = ((uint_t)u) << 16; return v.f;
}
// sigma16: swap middle two 4-blocks of each 16-group (involution).
// Makes S^T C-layout regs directly usable as the PV A-fragment.
static __device__ __forceinline__ int sig16(int n) {
  int g2 = (n >> 2) & 3;
  return (g2 == 1 || g2 == 2) ? (n ^ 0xC) : n;
}

typedef __attribute__((address_space(1))) void void_g;
typedef __attribute__((address_space(3))) void void_l;
static __device__ __forceinline__ void gload_lds16(const ushort_t* g, ushort_t* l) {
  __builtin_amdgcn_global_load_lds((void_g*)(ushort_t*)g, (void_l*)l, 16, 0, 0);
}

// ---------------------------------------------------------------------------
// MFMA projections. One 32-out-channel band per blockIdx.z:
//   z=0: Q (Wq, scaled log2e, + xhat cols 32..47)   z=1: K (Wk, + xhat)
//   z=2..5: V rows (z-2)*32 -> Vt[b][ch][sig16(n)]
// Each wave computes one 32x32 C tile (32 n-cols). Bias folded into C-init.
// C layout (verified): col = lane&31, row = (r&3)+8*(r>>2)+4*(lane>>5).
// ---------------------------------------------------------------------------
__global__ __launch_bounds__(256, 2)
void projm_kernel(const float* __restrict__ x, const float* __restrict__ xyz,
                  const float* __restrict__ Wq, const float* __restrict__ bq,
                  const float* __restrict__ Wk, const float* __restrict__ bk,
                  const float* __restrict__ Wv, const float* __restrict__ bv,
                  ushort_t* __restrict__ Qb, ushort_t* __restrict__ Kb,
                  ushort_t* __restrict__ Vt) {
  const int tid = threadIdx.x;
  const int lane = tid & 63, wv = tid >> 6;
  const int l31 = lane & 31, h = lane >> 5;
  const int b = blockIdx.y, z = blockIdx.z;
  const int n = blockIdx.x * 128 + wv * 32 + l31;

  const float* W; const float* bias; float sc;
  if (z == 0)      { W = Wq; bias = bq; sc = LOG2E; }
  else if (z == 1) { W = Wk; bias = bk; sc = 1.f; }
  else { W = Wv + (size_t)(z - 2) * 32 * 128; bias = bv + (z - 2) * 32; sc = 1.f; }

  // A-frags: A[m=l31][k = ks*16 + h*8 + j] = W[m][k] * sc
  bf16x8 af[8];
#pragma unroll
  for (int ks = 0; ks < 8; ++ks) {
    const float* wr = W + l31 * 128 + ks * 16 + h * 8;
    float4 w0 = *(const float4*)wr;
    float4 w1 = *(const float4*)(wr + 4);
    union { ushort_t u[8]; bf16x8 v; } p;
    p.u[0] = f2bf(w0.x * sc); p.u[1] = f2bf(w0.y * sc);
    p.u[2] = f2bf(w0.z * sc); p.u[3] = f2bf(w0.w * sc);
    p.u[4] = f2bf(w1.x * sc); p.u[5] = f2bf(w1.y * sc);
    p.u[6] = f2bf(w1.z * sc); p.u[7] = f2bf(w1.w * sc);
    af[ks] = p.v;
  }

  // bias C-init (row formula), scaled
  f32x16 S;
#pragma unroll
  for (int r = 0; r < 16; ++r)
    S[r] = bias[(r & 3) + 8 * (r >> 2) + 4 * h] * sc;

  // B-frags from x (coalesced per c-row), chained MFMA
  const float* xb = x + (size_t)b * NCH * NPTS + n;
#pragma unroll
  for (int ks = 0; ks < 8; ++ks) {
    const float* xc = xb + (size_t)(ks * 16 + h * 8) * NPTS;
    union { ushort_t u[8]; bf16x8 v; } p;
#pragma unroll
    for (int j = 0; j < 8; ++j) p.u[j] = f2bf(xc[(size_t)j * NPTS]);
    S = __builtin_amdgcn_mfma_f32_32x32x16_bf16(af[ks], p.v, S, 0, 0, 0);
  }

  if (z <= 1) {
    ushort_t* dst = (z == 0 ? Qb : Kb) + ((size_t)b * NPTS + n) * DQK;
#pragma unroll
    for (int r = 0; r < 16; ++r)
      dst[(r & 3) + 8 * (r >> 2) + 4 * h] = f2bf(S[r]);
    // xhat cols 32..34 (+ zeros to 47)
    float xa = xyz[((size_t)b * NPTS + n) * 3 + 0];
    float xc = xyz[((size_t)b * NPTS + n) * 3 + 1];
    float xd = xyz[((size_t)b * NPTS + n) * 3 + 2];
    float rn = 0.31622776601683794f * sc /
               (sqrtf(xa * xa + xc * xc + xd * xd) + 1e-8f);
    union { ushort_t u[16]; bf16x8 v[2]; } t;
#pragma unroll
    for (int j = 0; j < 16; ++j) t.u[j] = 0;
    t.u[0] = f2bf(xa * rn); t.u[1] = f2bf(xc * rn); t.u[2] = f2bf(xd * rn);
    *(bf16x8*)(dst + 32) = t.v[0];
    *(bf16x8*)(dst + 40) = t.v[1];
  } else {
    const int np = (n & ~15) | sig16(n & 15);  // key-permuted V storage
    const int c0 = (z - 2) * 32;
#pragma unroll
    for (int r = 0; r < 16; ++r)
      Vt[((size_t)b * NCH + c0 + (r & 3) + 8 * (r >> 2) + 4 * h) * NPTS + np] =
          f2bf(S[r]);
  }
}

// ---------------------------------------------------------------------------
// MFMA flash attention, 32x32x16, 64 q/wave, 8 waves = 512 q/block.
// Double-buffered global_load_lds staging, one barrier per round.
// Zero-init C + explicit exp2(S - SH2) (NO loop-invariant vector constant:
// a 16-reg C-init splat tips the 256-reg budget into scratch spill - R7).
// V is sigma16-permuted so S^T C-regs pack directly into the PV A-frag.
// ---------------------------------------------------------------------------
__global__ __launch_bounds__(512, 2)
void attn32_kernel(const ushort_t* __restrict__ Qb, const ushort_t* __restrict__ Kb,
                   const ushort_t* __restrict__ Vt,
                   ushort_t* __restrict__ PACC, float* __restrict__ PL) {
  // frag f: K = kb*3+c (6), V = 6 + fch*4 + kk (16); each 64 lanes x 16B
  __shared__ __align__(16) ushort_t L[2][22][512];
  const int tid = threadIdx.x;
  const int lane = tid & 63, w = tid >> 6;
  const int l31 = lane & 31, h = lane >> 5;

  const int lin = blockIdx.x;
  const int bs = lin & 15;          // XCD x sees bs in {x, x+8}: 2 (b,seg) combos
  const int b = bs & 3, sseg = bs >> 2;
  const int qblk = lin >> 4;        // 0..15
  const int q0w = qblk * 512 + w * 64;
  const int m00 = sseg * KEYS_PER;

  // persistent Q^T B-frags: q = q0w + g*32 + l31, d = c*16 + h*8 + j
  bf16x8 qf[2][3];
#pragma unroll
  for (int g = 0; g < 2; ++g)
#pragma unroll
    for (int c = 0; c < 3; ++c)
      qf[g][c] = *(const bf16x8*)(Qb + ((size_t)b * NPTS + q0w + g * 32 + l31) * DQK +
                                  c * 16 + h * 8);

  // staging: wave w handles frags {w, w+8, w+16} (22 total)
  const ushort_t* gp[3];
  int fid[3], adv[3];
  const int nf = (w < 6) ? 3 : 2;
  for (int i = 0; i < nf; ++i) {
    int fi = w + 8 * i;
    fid[i] = fi;
    if (fi < 6) {
      int kb = fi / 3, c = fi - kb * 3;
      gp[i] = Kb + ((size_t)b * NPTS + m00 + kb * 32 + l31) * DQK + c * 16 + h * 8;
      adv[i] = TK * DQK;
    } else {
      int vi = fi - 6, fch = vi >> 2, kk = vi & 3;
      gp[i] = Vt + ((size_t)b * NCH + fch * 32 + l31) * NPTS + m00 + kk * 16 + h * 8;
      adv[i] = TK;
    }
  }

  f32x16 O[2][4];
#pragma unroll
  for (int g = 0; g < 2; ++g)
#pragma unroll
    for (int f = 0; f < 4; ++f) O[g][f] = (f32x16)(0.f);
  float lsum0 = 0.f, lsum1 = 0.f;

  // prologue: stage round 0 into buffer 0
  for (int i = 0; i < nf; ++i) gload_lds16(gp[i], &L[0][fid[i]][0]);

#pragma unroll 1
  for (int t = 0; t < ROUNDS; ++t) {
    __syncthreads();  // auto vmcnt(0): buf[t&1] DMA (issued a full round ago) drained
    const int cur = t & 1;
    if (t + 1 < ROUNDS) {
      for (int i = 0; i < nf; ++i) {
        gp[i] += adv[i];
        gload_lds16(gp[i], &L[cur ^ 1][fid[i]][0]);  // overlaps compute below
      }
    }

#pragma unroll
    for (int kb = 0; kb < 2; ++kb) {
      bf16x8 kf0 = *(const bf16x8*)(&L[cur][kb * 3 + 0][0] + lane * 8);
      bf16x8 kf1 = *(const bf16x8*)(&L[cur][kb * 3 + 1][0] + lane * 8);
      bf16x8 kf2 = *(const bf16x8*)(&L[cur][kb * 3 + 2][0] + lane * 8);

      uint_t pk[2][8];
#pragma unroll
      for (int g = 0; g < 2; ++g) {
        f32x16 S = __builtin_amdgcn_mfma_f32_32x32x16_bf16(kf0, qf[g][0], (f32x16)(0.f), 0, 0, 0);
        S = __builtin_amdgcn_mfma_f32_32x32x16_bf16(kf1, qf[g][1], S, 0, 0, 0);
        S = __builtin_amdgcn_mfma_f32_32x32x16_bf16(kf2, qf[g][2], S, 0, 0, 0);
        float p[16];
        float ts = 0.f;
#pragma unroll
        for (int r = 0; r < 16; ++r) {
          p[r] = __builtin_amdgcn_exp2f(S[r] - SH2);
          ts += p[r];
        }
        if (g == 0) lsum0 += ts; else lsum1 += ts;
#pragma unroll
        for (int i = 0; i < 8; ++i)
          pk[g][i] = __builtin_amdgcn_perm(__float_as_uint(p[2 * i + 1]),
                                           __float_as_uint(p[2 * i]), 0x07060302u);
      }

      // sigma16-permuted V => C-regs pack directly into PV A-frags
#pragma unroll
      for (int kkl = 0; kkl < 2; ++kkl) {
        bf16x8 A[2];
#pragma unroll
        for (int g = 0; g < 2; ++g) {
          union { uint_t u[4]; bf16x8 v; } au;
          au.u[0] = pk[g][4 * kkl + 0];
          au.u[1] = pk[g][4 * kkl + 1];
          au.u[2] = pk[g][4 * kkl + 2];
          au.u[3] = pk[g][4 * kkl + 3];
          A[g] = au.v;
        }
#pragma unroll
        for (int f = 0; f < 4; ++f) {
          bf16x8 vf = *(const bf16x8*)(&L[cur][6 + f * 4 + kb * 2 + kkl][0] + lane * 8);
          O[0][f] = __builtin_amdgcn_mfma_f32_32x32x16_bf16(A[0], vf, O[0][f], 0, 0, 0);
          O[1][f] = __builtin_amdgcn_mfma_f32_32x32x16_bf16(A[1], vf, O[1][f], 0, 0, 0);
        }
      }
    }
  }

  // epilogue
  lsum0 += __shfl_xor(lsum0, 32);
  lsum1 += __shfl_xor(lsum1, 32);
  const size_t pbase = (((size_t)bs * 16 + qblk) * 8 + w) * 2;
#pragma unroll
  for (int g = 0; g < 2; ++g) {
#pragma unroll
    for (int f = 0; f < 4; ++f) {
      union { ushort_t u[16]; bf16x8 v[2]; } pu;
#pragma unroll
      for (int r = 0; r < 16; ++r) pu.u[r] = f2bf(O[g][f][r]);
      size_t idx = ((pbase + g) * 4 + f) * 1024 + (size_t)lane * 16;
      *(bf16x8*)(PACC + idx) = pu.v[0];
      *(bf16x8*)(PACC + idx + 8) = pu.v[1];
    }
    if (lane < 32)
      PL[(size_t)bs * NPTS + q0w + g * 32 + lane] = (g == 0) ? lsum0 : lsum1;
  }
}

// ---------------------------------------------------------------------------
// Merge 4 key-split partials (linear) + gamma + x.
// grid (qblk2 32, b 4, f 4); each block: 256 q x 32 ch.
// ---------------------------------------------------------------------------
__global__ __launch_bounds__(256, 4)
void merge4_kernel(const ushort_t* __restrict__ PACC, const float* __restrict__ PL,
                   const float* __restrict__ x, const float* __restrict__ gamma,
                   float* __restrict__ out) {
  __shared__ float Linv[256];
  const int tid = threadIdx.x;
  const int qblk2 = blockIdx.x, b = blockIdx.y, f = blockIdx.z;
  const int q0 = qblk2 * 256;

  float Ls = 0.f;
#pragma unroll
  for (int s = 0; s < 4; ++s)
    Ls += PL[(size_t)(s * 4 + b) * NPTS + q0 + tid];
  Linv[tid] = gamma[0] / Ls;
  __syncthreads();

  const int ww = tid >> 6, lane = tid & 63, l31 = lane & 31, h = lane >> 5;
  const int ch = f * 32 + l31;
  const float* xrow = x + ((size_t)b * NCH + ch) * NPTS + q0;
  float* orow = out + ((size_t)b * NCH + ch) * NPTS + q0;

#pragma unroll
  for (int g = 0; g < 2; ++g) {
    float acc[16];
#pragma unroll
    for (int r = 0; r < 16; ++r) acc[r] = 0.f;
#pragma unroll
    for (int s = 0; s < 4; ++s) {
      size_t idx = (((((size_t)(s * 4 + b) * 16 + (qblk2 >> 1)) * 8 +
                      (qblk2 & 1) * 4 + ww) * 2 + g) * 4 + f) * 1024 +
                   (size_t)lane * 16;
      bf16x8 a0 = *(const bf16x8*)(PACC + idx);
      bf16x8 a1 = *(const bf16x8*)(PACC + idx + 8);
#pragma unroll
      for (int r = 0; r < 8; ++r) {
        acc[r] += bf2f((ushort_t)a0[r]);
        acc[8 + r] += bf2f((ushort_t)a1[r]);
      }
    }
    const int qb = ww * 64 + g * 32;
#pragma unroll
    for (int rr = 0; rr < 4; ++rr) {
      int q = qb + 8 * rr + 4 * h;
      f32x4 xv = *(const f32x4*)(xrow + q);
      f32x4 o;
#pragma unroll
      for (int i = 0; i < 4; ++i) o[i] = acc[rr * 4 + i] * Linv[q + i] + xv[i];
      *(f32x4*)(orow + q) = o;
    }
  }
}

// ---------------------------------------------------------------------------
extern "C" void kernel_launch(void* const* d_in, const int* in_sizes, int n_in,
                              void* d_out, int out_size, void* d_ws,
                              size_t ws_size, hipStream_t stream) {
  const float* x     = (const float*)d_in[0];
  const float* xyz   = (const float*)d_in[1];
  const float* Wq    = (const float*)d_in[2];
  const float* bq    = (const float*)d_in[3];
  const float* Wk    = (const float*)d_in[4];
  const float* bk    = (const float*)d_in[5];
  const float* Wv    = (const float*)d_in[6];
  const float* bv    = (const float*)d_in[7];
  const float* gamma = (const float*)d_in[8];
  float* out = (float*)d_out;

  const size_t BN = (size_t)NB * NPTS;
  ushort_t* Qb = (ushort_t*)d_ws;
  ushort_t* Kb = Qb + BN * DQK;
  ushort_t* Vt = Kb + BN * DQK;
  ushort_t* PACC = Vt + BN * NCH;   // 16 bs * 16 qblk * 8 w * 2 g * 4 f * 1024
  float* PL = (float*)(PACC + (size_t)16 * 16 * 8 * 2 * 4 * 1024);

  projm_kernel<<<dim3(NPTS / 128, NB, 6), 256, 0, stream>>>(
      x, xyz, Wq, bq, Wk, bk, Wv, bv, Qb, Kb, Vt);
  attn32_kernel<<<256, 512, 0, stream>>>(Qb, Kb, Vt, PACC, PL);
  merge4_kernel<<<dim3(32, NB, 4), 256, 0, stream>>>(PACC, PL, x, gamma, out);
  (void)in_sizes; (void)n_in; (void)out_size; (void)ws_size;
}

// Round 9
// 201.316 us; speedup vs baseline: 15.1692x; 1.0149x over previous
//
#include <hip/hip_runtime.h>

#define NPTS 8192
#define NB 4
#define NCH 128
#define DQK 48
#define TK 64
#define SPLIT 4
#define KEYS_PER (NPTS / SPLIT)   // 2048
#define ROUNDS (KEYS_PER / TK)    // 32
#define SH2 28.853901f            // 20 * log2(e)
#define LOG2E 1.4426950408889634f

typedef unsigned short ushort_t;
typedef unsigned int uint_t;
typedef __attribute__((ext_vector_type(8))) short bf16x8;
typedef __attribute__((ext_vector_type(4))) float f32x4;
typedef __attribute__((ext_vector_type(16))) float f32x16;

static __device__ __forceinline__ ushort_t f2bf(float x) {
  union { float f; uint_t u; } v; v.f = x;
  uint_t r = v.u + 0x7fffu + ((v.u >> 16) & 1u);
  return (ushort_t)(r >> 16);
}
static __device__ __forceinline__ float bf2f(ushort_t u) {
  union { uint_t i; float f; } v; v.i = ((uint_t)u) << 16; return v.f;
}
// sigma16: swap middle two 4-blocks of each 16-group (involution).
// Makes S^T C-layout regs directly usable as the PV A-fragment.
static __device__ __forceinline__ int sig16(int n) {
  int g2 = (n >> 2) & 3;
  return (g2 == 1 || g2 == 2) ? (n ^ 0xC) : n;
}

typedef __attribute__((address_space(1))) void void_g;
typedef __attribute__((address_space(3))) void void_l;
static __device__ __forceinline__ void gload_lds16(const ushort_t* g, ushort_t* l) {
  __builtin_amdgcn_global_load_lds((void_g*)(ushort_t*)g, (void_l*)l, 16, 0, 0);
}

// ---------------------------------------------------------------------------
// Weight prep: W -> A-fragment-ordered bf16 Wb[z][ks][lane][8] (log2e folded
// into z=0), plus fused scaled bias bias_pre[192]. 6 blocks, one z each.
// ---------------------------------------------------------------------------
__global__ __launch_bounds__(512, 1)
void wprep_kernel(const float* __restrict__ Wq, const float* __restrict__ bq,
                  const float* __restrict__ Wk, const float* __restrict__ bk,
                  const float* __restrict__ Wv, const float* __restrict__ bv,
                  ushort_t* __restrict__ Wb, float* __restrict__ bias_pre) {
  const int z = blockIdx.x;
  const int ks = threadIdx.x >> 6;
  const int lane = threadIdx.x & 63;
  const int l31 = lane & 31, h = lane >> 5;
  const float* W = (z == 0) ? Wq : (z == 1) ? Wk : (Wv + (size_t)(z - 2) * 32 * 128);
  const float sc = (z == 0) ? LOG2E : 1.0f;
  const float* wr = W + l31 * 128 + ks * 16 + h * 8;
  union { ushort_t u[8]; bf16x8 v; } p;
#pragma unroll
  for (int j = 0; j < 8; ++j) p.u[j] = f2bf(wr[j] * sc);
  *(bf16x8*)(Wb + ((size_t)(z * 8 + ks) * 64 + lane) * 8) = p.v;
  if (z == 0 && threadIdx.x < 192) {
    int i = threadIdx.x;
    bias_pre[i] = (i < 32) ? bq[i] * LOG2E : (i < 64) ? bk[i - 32] : bv[i - 64];
  }
}

// ---------------------------------------------------------------------------
// MFMA projections, fused over all 6 bands: x B-frags loaded+converted ONCE
// per wave (32 n-cols), reused for 48 MFMAs. A-frags from pre-packed Wb
// (coalesced 16B loads). C layout: col = lane&31, row = (r&3)+8*(r>>2)+4h.
// z=0: Qb rows (+xhat, log2e-scaled), z=1: Kb rows (+xhat), z=2..5: Vt with
// sigma16-permuted key index.
// ---------------------------------------------------------------------------
__global__ __launch_bounds__(256, 4)
void projm2_kernel(const float* __restrict__ x, const float* __restrict__ xyz,
                   const ushort_t* __restrict__ Wb,
                   const float* __restrict__ bias_pre,
                   ushort_t* __restrict__ Qb, ushort_t* __restrict__ Kb,
                   ushort_t* __restrict__ Vt) {
  const int tid = threadIdx.x;
  const int lane = tid & 63, wv = tid >> 6;
  const int l31 = lane & 31, h = lane >> 5;
  const int b = blockIdx.y;
  const int n = blockIdx.x * 128 + wv * 32 + l31;

  // B-frags from x (coalesced per c-row), converted once, reused 6x
  bf16x8 bfr[8];
  const float* xb = x + (size_t)b * NCH * NPTS + n;
#pragma unroll
  for (int ks = 0; ks < 8; ++ks) {
    const float* xc = xb + (size_t)(ks * 16 + h * 8) * NPTS;
    union { ushort_t u[8]; bf16x8 v; } p;
#pragma unroll
    for (int j = 0; j < 8; ++j) p.u[j] = f2bf(xc[(size_t)j * NPTS]);
    bfr[ks] = p.v;
  }

  // xhat (bands 0,1)
  float xa = xyz[((size_t)b * NPTS + n) * 3 + 0];
  float xc2 = xyz[((size_t)b * NPTS + n) * 3 + 1];
  float xd = xyz[((size_t)b * NPTS + n) * 3 + 2];
  float rinv = 1.0f / (sqrtf(xa * xa + xc2 * xc2 + xd * xd) + 1e-8f);

#pragma unroll 1
  for (int z = 0; z < 6; ++z) {
    f32x16 S;
#pragma unroll
    for (int r = 0; r < 16; ++r)
      S[r] = bias_pre[z * 32 + (r & 3) + 8 * (r >> 2) + 4 * h];
#pragma unroll
    for (int ks = 0; ks < 8; ++ks) {
      bf16x8 af = *(const bf16x8*)(Wb + ((size_t)(z * 8 + ks) * 64 + lane) * 8);
      S = __builtin_amdgcn_mfma_f32_32x32x16_bf16(af, bfr[ks], S, 0, 0, 0);
    }
    if (z <= 1) {
      float sc = (z == 0) ? LOG2E : 1.0f;
      ushort_t* dst = (z == 0 ? Qb : Kb) + ((size_t)b * NPTS + n) * DQK;
#pragma unroll
      for (int r = 0; r < 16; ++r)
        dst[(r & 3) + 8 * (r >> 2) + 4 * h] = f2bf(S[r]);
      float rn = 0.31622776601683794f * sc * rinv;
      union { ushort_t u[16]; bf16x8 v[2]; } t;
#pragma unroll
      for (int j = 0; j < 16; ++j) t.u[j] = 0;
      t.u[0] = f2bf(xa * rn); t.u[1] = f2bf(xc2 * rn); t.u[2] = f2bf(xd * rn);
      *(bf16x8*)(dst + 32) = t.v[0];
      *(bf16x8*)(dst + 40) = t.v[1];
    } else {
      const int np = (n & ~15) | sig16(n & 15);  // key-permuted V storage
      const int c0 = (z - 2) * 32;
#pragma unroll
      for (int r = 0; r < 16; ++r)
        Vt[((size_t)b * NCH + c0 + (r & 3) + 8 * (r >> 2) + 4 * h) * NPTS + np] =
            f2bf(S[r]);
    }
  }
}

// ---------------------------------------------------------------------------
// MFMA flash attention, 32x32x16, 64 q/wave, 8 waves = 512 q/block.
// Double-buffered global_load_lds staging, one barrier per round.
// Zero-init C + explicit exp2(S - SH2) (NO loop-invariant vector constant:
// a 16-reg C-init splat tips the 256-reg budget into scratch spill - R7).
// V is sigma16-permuted so S^T C-regs pack directly into the PV A-frag.
// ---------------------------------------------------------------------------
__global__ __launch_bounds__(512, 2)
void attn32_kernel(const ushort_t* __restrict__ Qb, const ushort_t* __restrict__ Kb,
                   const ushort_t* __restrict__ Vt,
                   ushort_t* __restrict__ PACC, float* __restrict__ PL) {
  // frag f: K = kb*3+c (6), V = 6 + fch*4 + kk (16); each 64 lanes x 16B
  __shared__ __align__(16) ushort_t L[2][22][512];
  const int tid = threadIdx.x;
  const int lane = tid & 63, w = tid >> 6;
  const int l31 = lane & 31, h = lane >> 5;

  const int lin = blockIdx.x;
  const int bs = lin & 15;          // XCD x sees bs in {x, x+8}: 2 (b,seg) combos
  const int b = bs & 3, sseg = bs >> 2;
  const int qblk = lin >> 4;        // 0..15
  const int q0w = qblk * 512 + w * 64;
  const int m00 = sseg * KEYS_PER;

  // persistent Q^T B-frags: q = q0w + g*32 + l31, d = c*16 + h*8 + j
  bf16x8 qf[2][3];
#pragma unroll
  for (int g = 0; g < 2; ++g)
#pragma unroll
    for (int c = 0; c < 3; ++c)
      qf[g][c] = *(const bf16x8*)(Qb + ((size_t)b * NPTS + q0w + g * 32 + l31) * DQK +
                                  c * 16 + h * 8);

  // staging: wave w handles frags {w, w+8, w+16} (22 total)
  const ushort_t* gp[3];
  int fid[3], adv[3];
  const int nf = (w < 6) ? 3 : 2;
  for (int i = 0; i < nf; ++i) {
    int fi = w + 8 * i;
    fid[i] = fi;
    if (fi < 6) {
      int kb = fi / 3, c = fi - kb * 3;
      gp[i] = Kb + ((size_t)b * NPTS + m00 + kb * 32 + l31) * DQK + c * 16 + h * 8;
      adv[i] = TK * DQK;
    } else {
      int vi = fi - 6, fch = vi >> 2, kk = vi & 3;
      gp[i] = Vt + ((size_t)b * NCH + fch * 32 + l31) * NPTS + m00 + kk * 16 + h * 8;
      adv[i] = TK;
    }
  }

  f32x16 O[2][4];
#pragma unroll
  for (int g = 0; g < 2; ++g)
#pragma unroll
    for (int f = 0; f < 4; ++f) O[g][f] = (f32x16)(0.f);
  float lsum0 = 0.f, lsum1 = 0.f;

  // prologue: stage round 0 into buffer 0
  for (int i = 0; i < nf; ++i) gload_lds16(gp[i], &L[0][fid[i]][0]);

#pragma unroll 1
  for (int t = 0; t < ROUNDS; ++t) {
    __syncthreads();  // auto vmcnt(0): buf[t&1] DMA (issued a full round ago) drained
    const int cur = t & 1;
    if (t + 1 < ROUNDS) {
      for (int i = 0; i < nf; ++i) {
        gp[i] += adv[i];
        gload_lds16(gp[i], &L[cur ^ 1][fid[i]][0]);  // overlaps compute below
      }
    }

#pragma unroll
    for (int kb = 0; kb < 2; ++kb) {
      bf16x8 kf0 = *(const bf16x8*)(&L[cur][kb * 3 + 0][0] + lane * 8);
      bf16x8 kf1 = *(const bf16x8*)(&L[cur][kb * 3 + 1][0] + lane * 8);
      bf16x8 kf2 = *(const bf16x8*)(&L[cur][kb * 3 + 2][0] + lane * 8);

      uint_t pk[2][8];
#pragma unroll
      for (int g = 0; g < 2; ++g) {
        f32x16 S = __builtin_amdgcn_mfma_f32_32x32x16_bf16(kf0, qf[g][0], (f32x16)(0.f), 0, 0, 0);
        S = __builtin_amdgcn_mfma_f32_32x32x16_bf16(kf1, qf[g][1], S, 0, 0, 0);
        S = __builtin_amdgcn_mfma_f32_32x32x16_bf16(kf2, qf[g][2], S, 0, 0, 0);
        float p[16];
        float ts = 0.f;
#pragma unroll
        for (int r = 0; r < 16; ++r) {
          p[r] = __builtin_amdgcn_exp2f(S[r] - SH2);
          ts += p[r];
        }
        if (g == 0) lsum0 += ts; else lsum1 += ts;
#pragma unroll
        for (int i = 0; i < 8; ++i)
          pk[g][i] = __builtin_amdgcn_perm(__float_as_uint(p[2 * i + 1]),
                                           __float_as_uint(p[2 * i]), 0x07060302u);
      }

      // sigma16-permuted V => C-regs pack directly into PV A-frags
#pragma unroll
      for (int kkl = 0; kkl < 2; ++kkl) {
        bf16x8 A[2];
#pragma unroll
        for (int g = 0; g < 2; ++g) {
          union { uint_t u[4]; bf16x8 v; } au;
          au.u[0] = pk[g][4 * kkl + 0];
          au.u[1] = pk[g][4 * kkl + 1];
          au.u[2] = pk[g][4 * kkl + 2];
          au.u[3] = pk[g][4 * kkl + 3];
          A[g] = au.v;
        }
#pragma unroll
        for (int f = 0; f < 4; ++f) {
          bf16x8 vf = *(const bf16x8*)(&L[cur][6 + f * 4 + kb * 2 + kkl][0] + lane * 8);
          O[0][f] = __builtin_amdgcn_mfma_f32_32x32x16_bf16(A[0], vf, O[0][f], 0, 0, 0);
          O[1][f] = __builtin_amdgcn_mfma_f32_32x32x16_bf16(A[1], vf, O[1][f], 0, 0, 0);
        }
      }
    }
  }

  // epilogue
  lsum0 += __shfl_xor(lsum0, 32);
  lsum1 += __shfl_xor(lsum1, 32);
  const size_t pbase = (((size_t)bs * 16 + qblk) * 8 + w) * 2;
#pragma unroll
  for (int g = 0; g < 2; ++g) {
#pragma unroll
    for (int f = 0; f < 4; ++f) {
      union { ushort_t u[16]; bf16x8 v[2]; } pu;
#pragma unroll
      for (int r = 0; r < 16; ++r) pu.u[r] = f2bf(O[g][f][r]);
      size_t idx = ((pbase + g) * 4 + f) * 1024 + (size_t)lane * 16;
      *(bf16x8*)(PACC + idx) = pu.v[0];
      *(bf16x8*)(PACC + idx + 8) = pu.v[1];
    }
    if (lane < 32)
      PL[(size_t)bs * NPTS + q0w + g * 32 + lane] = (g == 0) ? lsum0 : lsum1;
  }
}

// ---------------------------------------------------------------------------
// Merge 4 key-split partials (linear) + gamma + x.
// grid (qblk2 32, b 4, f 4); each block: 256 q x 32 ch.
// ---------------------------------------------------------------------------
__global__ __launch_bounds__(256, 4)
void merge4_kernel(const ushort_t* __restrict__ PACC, const float* __restrict__ PL,
                   const float* __restrict__ x, const float* __restrict__ gamma,
                   float* __restrict__ out) {
  __shared__ float Linv[256];
  const int tid = threadIdx.x;
  const int qblk2 = blockIdx.x, b = blockIdx.y, f = blockIdx.z;
  const int q0 = qblk2 * 256;

  float Ls = 0.f;
#pragma unroll
  for (int s = 0; s < 4; ++s)
    Ls += PL[(size_t)(s * 4 + b) * NPTS + q0 + tid];
  Linv[tid] = gamma[0] / Ls;
  __syncthreads();

  const int ww = tid >> 6, lane = tid & 63, l31 = lane & 31, h = lane >> 5;
  const int ch = f * 32 + l31;
  const float* xrow = x + ((size_t)b * NCH + ch) * NPTS + q0;
  float* orow = out + ((size_t)b * NCH + ch) * NPTS + q0;

#pragma unroll
  for (int g = 0; g < 2; ++g) {
    float acc[16];
#pragma unroll
    for (int r = 0; r < 16; ++r) acc[r] = 0.f;
#pragma unroll
    for (int s = 0; s < 4; ++s) {
      size_t idx = (((((size_t)(s * 4 + b) * 16 + (qblk2 >> 1)) * 8 +
                      (qblk2 & 1) * 4 + ww) * 2 + g) * 4 + f) * 1024 +
                   (size_t)lane * 16;
      bf16x8 a0 = *(const bf16x8*)(PACC + idx);
      bf16x8 a1 = *(const bf16x8*)(PACC + idx + 8);
#pragma unroll
      for (int r = 0; r < 8; ++r) {
        acc[r] += bf2f((ushort_t)a0[r]);
        acc[8 + r] += bf2f((ushort_t)a1[r]);
      }
    }
    const int qb = ww * 64 + g * 32;
#pragma unroll
    for (int rr = 0; rr < 4; ++rr) {
      int q = qb + 8 * rr + 4 * h;
      f32x4 xv = *(const f32x4*)(xrow + q);
      f32x4 o;
#pragma unroll
      for (int i = 0; i < 4; ++i) o[i] = acc[rr * 4 + i] * Linv[q + i] + xv[i];
      *(f32x4*)(orow + q) = o;
    }
  }
}

// ---------------------------------------------------------------------------
extern "C" void kernel_launch(void* const* d_in, const int* in_sizes, int n_in,
                              void* d_out, int out_size, void* d_ws,
                              size_t ws_size, hipStream_t stream) {
  const float* x     = (const float*)d_in[0];
  const float* xyz   = (const float*)d_in[1];
  const float* Wq    = (const float*)d_in[2];
  const float* bq    = (const float*)d_in[3];
  const float* Wk    = (const float*)d_in[4];
  const float* bk    = (const float*)d_in[5];
  const float* Wv    = (const float*)d_in[6];
  const float* bv    = (const float*)d_in[7];
  const float* gamma = (const float*)d_in[8];
  float* out = (float*)d_out;

  const size_t BN = (size_t)NB * NPTS;
  ushort_t* Qb = (ushort_t*)d_ws;
  ushort_t* Kb = Qb + BN * DQK;
  ushort_t* Vt = Kb + BN * DQK;
  ushort_t* PACC = Vt + BN * NCH;   // 16 bs * 16 qblk * 8 w * 2 g * 4 f * 1024
  float* PL = (float*)(PACC + (size_t)16 * 16 * 8 * 2 * 4 * 1024);
  ushort_t* Wb = (ushort_t*)(PL + 16 * BN / 2);  // 6*8*64*8 = 24576 ushort
  float* bias_pre = (float*)(Wb + 6 * 8 * 64 * 8);

  wprep_kernel<<<6, 512, 0, stream>>>(Wq, bq, Wk, bk, Wv, bv, Wb, bias_pre);
  projm2_kernel<<<dim3(NPTS / 128, NB), 256, 0, stream>>>(
      x, xyz, Wb, bias_pre, Qb, Kb, Vt);
  attn32_kernel<<<256, 512, 0, stream>>>(Qb, Kb, Vt, PACC, PL);
  merge4_kernel<<<dim3(32, NB, 4), 256, 0, stream>>>(PACC, PL, x, gamma, out);
  (void)in_sizes; (void)n_in; (void)out_size; (void)ws_size;
}

// Round 10
// 198.098 us; speedup vs baseline: 15.4156x; 1.0162x over previous
//
#include <hip/hip_runtime.h>

#define NPTS 8192
#define NB 4
#define NCH 128
#define DQK 48
#define TK 64
#define SPLIT 4
#define KEYS_PER (NPTS / SPLIT)   // 2048
#define ROUNDS (KEYS_PER / TK)    // 32
#define SH2 28.853901f            // 20 * log2(e)
#define LOG2E 1.4426950408889634f

typedef unsigned short ushort_t;
typedef unsigned int uint_t;
typedef __attribute__((ext_vector_type(8))) short bf16x8;
typedef __attribute__((ext_vector_type(4))) float f32x4;
typedef __attribute__((ext_vector_type(16))) float f32x16;

static __device__ __forceinline__ ushort_t f2bf(float x) {
  union { float f; uint_t u; } v; v.f = x;
  uint_t r = v.u + 0x7fffu + ((v.u >> 16) & 1u);
  return (ushort_t)(r >> 16);
}
static __device__ __forceinline__ float bf2f(ushort_t u) {
  union { uint_t i; float f; } v; v.i = ((uint_t)u) << 16; return v.f;
}
// sigma16: swap middle two 4-blocks of each 16-group (involution).
// Makes S^T C-layout regs directly usable as the PV A-fragment.
static __device__ __forceinline__ int sig16(int n) {
  int g2 = (n >> 2) & 3;
  return (g2 == 1 || g2 == 2) ? (n ^ 0xC) : n;
}

typedef __attribute__((address_space(1))) void void_g;
typedef __attribute__((address_space(3))) void void_l;
static __device__ __forceinline__ void gload_lds16(const ushort_t* g, ushort_t* l) {
  __builtin_amdgcn_global_load_lds((void_g*)(ushort_t*)g, (void_l*)l, 16, 0, 0);
}

// ---------------------------------------------------------------------------
// Weight prep: W -> A-fragment-ordered bf16 Wb[z][ks][lane][8] (log2e folded
// into z=0), plus fused scaled bias bias_pre[192]. 6 blocks, one z each.
// ---------------------------------------------------------------------------
__global__ __launch_bounds__(512, 1)
void wprep_kernel(const float* __restrict__ Wq, const float* __restrict__ bq,
                  const float* __restrict__ Wk, const float* __restrict__ bk,
                  const float* __restrict__ Wv, const float* __restrict__ bv,
                  ushort_t* __restrict__ Wb, float* __restrict__ bias_pre) {
  const int z = blockIdx.x;
  const int ks = threadIdx.x >> 6;
  const int lane = threadIdx.x & 63;
  const int l31 = lane & 31, h = lane >> 5;
  const float* W = (z == 0) ? Wq : (z == 1) ? Wk : (Wv + (size_t)(z - 2) * 32 * 128);
  const float sc = (z == 0) ? LOG2E : 1.0f;
  const float* wr = W + l31 * 128 + ks * 16 + h * 8;
  union { ushort_t u[8]; bf16x8 v; } p;
#pragma unroll
  for (int j = 0; j < 8; ++j) p.u[j] = f2bf(wr[j] * sc);
  *(bf16x8*)(Wb + ((size_t)(z * 8 + ks) * 64 + lane) * 8) = p.v;
  if (z == 0 && threadIdx.x < 192) {
    int i = threadIdx.x;
    bias_pre[i] = (i < 32) ? bq[i] * LOG2E : (i < 64) ? bk[i - 32] : bv[i - 64];
  }
}

// ---------------------------------------------------------------------------
// MFMA projections, fused over all 6 bands: x B-frags loaded+converted ONCE
// per wave (32 n-cols), reused for 48 MFMAs. A-frags from pre-packed Wb
// (coalesced 16B loads). C layout: col = lane&31, row = (r&3)+8*(r>>2)+4h.
// z=0: Qb rows (+xhat, log2e-scaled), z=1: Kb rows (+xhat), z=2..5: Vt with
// sigma16-permuted key index.
// ---------------------------------------------------------------------------
__global__ __launch_bounds__(256, 4)
void projm2_kernel(const float* __restrict__ x, const float* __restrict__ xyz,
                   const ushort_t* __restrict__ Wb,
                   const float* __restrict__ bias_pre,
                   ushort_t* __restrict__ Qb, ushort_t* __restrict__ Kb,
                   ushort_t* __restrict__ Vt) {
  const int tid = threadIdx.x;
  const int lane = tid & 63, wv = tid >> 6;
  const int l31 = lane & 31, h = lane >> 5;
  const int b = blockIdx.y;
  const int n = blockIdx.x * 128 + wv * 32 + l31;

  // B-frags from x (coalesced per c-row), converted once, reused 6x
  bf16x8 bfr[8];
  const float* xb = x + (size_t)b * NCH * NPTS + n;
#pragma unroll
  for (int ks = 0; ks < 8; ++ks) {
    const float* xc = xb + (size_t)(ks * 16 + h * 8) * NPTS;
    union { ushort_t u[8]; bf16x8 v; } p;
#pragma unroll
    for (int j = 0; j < 8; ++j) p.u[j] = f2bf(xc[(size_t)j * NPTS]);
    bfr[ks] = p.v;
  }

  // xhat (bands 0,1)
  float xa = xyz[((size_t)b * NPTS + n) * 3 + 0];
  float xc2 = xyz[((size_t)b * NPTS + n) * 3 + 1];
  float xd = xyz[((size_t)b * NPTS + n) * 3 + 2];
  float rinv = 1.0f / (sqrtf(xa * xa + xc2 * xc2 + xd * xd) + 1e-8f);

#pragma unroll 1
  for (int z = 0; z < 6; ++z) {
    f32x16 S;
#pragma unroll
    for (int r = 0; r < 16; ++r)
      S[r] = bias_pre[z * 32 + (r & 3) + 8 * (r >> 2) + 4 * h];
#pragma unroll
    for (int ks = 0; ks < 8; ++ks) {
      bf16x8 af = *(const bf16x8*)(Wb + ((size_t)(z * 8 + ks) * 64 + lane) * 8);
      S = __builtin_amdgcn_mfma_f32_32x32x16_bf16(af, bfr[ks], S, 0, 0, 0);
    }
    if (z <= 1) {
      float sc = (z == 0) ? LOG2E : 1.0f;
      ushort_t* dst = (z == 0 ? Qb : Kb) + ((size_t)b * NPTS + n) * DQK;
#pragma unroll
      for (int r = 0; r < 16; ++r)
        dst[(r & 3) + 8 * (r >> 2) + 4 * h] = f2bf(S[r]);
      float rn = 0.31622776601683794f * sc * rinv;
      union { ushort_t u[16]; bf16x8 v[2]; } t;
#pragma unroll
      for (int j = 0; j < 16; ++j) t.u[j] = 0;
      t.u[0] = f2bf(xa * rn); t.u[1] = f2bf(xc2 * rn); t.u[2] = f2bf(xd * rn);
      *(bf16x8*)(dst + 32) = t.v[0];
      *(bf16x8*)(dst + 40) = t.v[1];
    } else {
      const int np = (n & ~15) | sig16(n & 15);  // key-permuted V storage
      const int c0 = (z - 2) * 32;
#pragma unroll
      for (int r = 0; r < 16; ++r)
        Vt[((size_t)b * NCH + c0 + (r & 3) + 8 * (r >> 2) + 4 * h) * NPTS + np] =
            f2bf(S[r]);
    }
  }
}

// ---------------------------------------------------------------------------
// MFMA flash attention, 32x32x16, 64 q/wave, 8 waves = 512 q/block.
// Double-buffered global_load_lds staging, one barrier per round.
// Zero-init C + explicit exp2(S - SH2) (NO loop-invariant vector constant:
// a 16-reg C-init splat tips the 256-reg budget into scratch spill - R7).
// V is sigma16-permuted so S^T C-regs pack directly into the PV A-frag.
// ---------------------------------------------------------------------------
__global__ __launch_bounds__(512, 2)
void attn32_kernel(const ushort_t* __restrict__ Qb, const ushort_t* __restrict__ Kb,
                   const ushort_t* __restrict__ Vt,
                   ushort_t* __restrict__ PACC, float* __restrict__ PL) {
  // frag f: K = kb*3+c (6), V = 6 + fch*4 + kk (16); each 64 lanes x 16B
  __shared__ __align__(16) ushort_t L[2][22][512];
  const int tid = threadIdx.x;
  const int lane = tid & 63, w = tid >> 6;
  const int l31 = lane & 31, h = lane >> 5;

  const int lin = blockIdx.x;
  const int bs = lin & 15;          // XCD x sees bs in {x, x+8}: 2 (b,seg) combos
  const int b = bs & 3, sseg = bs >> 2;
  const int qblk = lin >> 4;        // 0..15
  const int q0w = qblk * 512 + w * 64;
  const int m00 = sseg * KEYS_PER;

  // persistent Q^T B-frags: q = q0w + g*32 + l31, d = c*16 + h*8 + j
  bf16x8 qf[2][3];
#pragma unroll
  for (int g = 0; g < 2; ++g)
#pragma unroll
    for (int c = 0; c < 3; ++c)
      qf[g][c] = *(const bf16x8*)(Qb + ((size_t)b * NPTS + q0w + g * 32 + l31) * DQK +
                                  c * 16 + h * 8);

  // staging: wave w handles frags {w, w+8, w+16} (22 total)
  const ushort_t* gp[3];
  int fid[3], adv[3];
  const int nf = (w < 6) ? 3 : 2;
  for (int i = 0; i < nf; ++i) {
    int fi = w + 8 * i;
    fid[i] = fi;
    if (fi < 6) {
      int kb = fi / 3, c = fi - kb * 3;
      gp[i] = Kb + ((size_t)b * NPTS + m00 + kb * 32 + l31) * DQK + c * 16 + h * 8;
      adv[i] = TK * DQK;
    } else {
      int vi = fi - 6, fch = vi >> 2, kk = vi & 3;
      gp[i] = Vt + ((size_t)b * NCH + fch * 32 + l31) * NPTS + m00 + kk * 16 + h * 8;
      adv[i] = TK;
    }
  }

  f32x16 O[2][4];
#pragma unroll
  for (int g = 0; g < 2; ++g)
#pragma unroll
    for (int f = 0; f < 4; ++f) O[g][f] = (f32x16)(0.f);
  float lsum0 = 0.f, lsum1 = 0.f;

  // prologue: stage round 0 into buffer 0
  for (int i = 0; i < nf; ++i) gload_lds16(gp[i], &L[0][fid[i]][0]);

#pragma unroll 1
  for (int t = 0; t < ROUNDS; ++t) {
    __syncthreads();  // auto vmcnt(0): buf[t&1] DMA (issued a full round ago) drained
    const int cur = t & 1;
    if (t + 1 < ROUNDS) {
      for (int i = 0; i < nf; ++i) {
        gp[i] += adv[i];
        gload_lds16(gp[i], &L[cur ^ 1][fid[i]][0]);  // overlaps compute below
      }
    }

#pragma unroll
    for (int kb = 0; kb < 2; ++kb) {
      bf16x8 kf0 = *(const bf16x8*)(&L[cur][kb * 3 + 0][0] + lane * 8);
      bf16x8 kf1 = *(const bf16x8*)(&L[cur][kb * 3 + 1][0] + lane * 8);
      bf16x8 kf2 = *(const bf16x8*)(&L[cur][kb * 3 + 2][0] + lane * 8);

      uint_t pk[2][8];
#pragma unroll
      for (int g = 0; g < 2; ++g) {
        f32x16 S = __builtin_amdgcn_mfma_f32_32x32x16_bf16(kf0, qf[g][0], (f32x16)(0.f), 0, 0, 0);
        S = __builtin_amdgcn_mfma_f32_32x32x16_bf16(kf1, qf[g][1], S, 0, 0, 0);
        S = __builtin_amdgcn_mfma_f32_32x32x16_bf16(kf2, qf[g][2], S, 0, 0, 0);
        float p[16];
        float ts = 0.f;
#pragma unroll
        for (int r = 0; r < 16; ++r) {
          p[r] = __builtin_amdgcn_exp2f(S[r] - SH2);
          ts += p[r];
        }
        if (g == 0) lsum0 += ts; else lsum1 += ts;
#pragma unroll
        for (int i = 0; i < 8; ++i)
          pk[g][i] = __builtin_amdgcn_perm(__float_as_uint(p[2 * i + 1]),
                                           __float_as_uint(p[2 * i]), 0x07060302u);
      }

      // sigma16-permuted V => C-regs pack directly into PV A-frags
#pragma unroll
      for (int kkl = 0; kkl < 2; ++kkl) {
        bf16x8 A[2];
#pragma unroll
        for (int g = 0; g < 2; ++g) {
          union { uint_t u[4]; bf16x8 v; } au;
          au.u[0] = pk[g][4 * kkl + 0];
          au.u[1] = pk[g][4 * kkl + 1];
          au.u[2] = pk[g][4 * kkl + 2];
          au.u[3] = pk[g][4 * kkl + 3];
          A[g] = au.v;
        }
#pragma unroll
        for (int f = 0; f < 4; ++f) {
          bf16x8 vf = *(const bf16x8*)(&L[cur][6 + f * 4 + kb * 2 + kkl][0] + lane * 8);
          O[0][f] = __builtin_amdgcn_mfma_f32_32x32x16_bf16(A[0], vf, O[0][f], 0, 0, 0);
          O[1][f] = __builtin_amdgcn_mfma_f32_32x32x16_bf16(A[1], vf, O[1][f], 0, 0, 0);
        }
      }
    }
  }

  // epilogue
  lsum0 += __shfl_xor(lsum0, 32);
  lsum1 += __shfl_xor(lsum1, 32);
  const size_t pbase = (((size_t)bs * 16 + qblk) * 8 + w) * 2;
#pragma unroll
  for (int g = 0; g < 2; ++g) {
#pragma unroll
    for (int f = 0; f < 4; ++f) {
      union { ushort_t u[16]; bf16x8 v[2]; } pu;
#pragma unroll
      for (int r = 0; r < 16; ++r) pu.u[r] = f2bf(O[g][f][r]);
      size_t idx = ((pbase + g) * 4 + f) * 1024 + (size_t)lane * 16;
      *(bf16x8*)(PACC + idx) = pu.v[0];
      *(bf16x8*)(PACC + idx + 8) = pu.v[1];
    }
    if (lane < 32)
      PL[(size_t)bs * NPTS + q0w + g * 32 + lane] = (g == 0) ? lsum0 : lsum1;
  }
}

// ---------------------------------------------------------------------------
// Merge 4 key-split partials + gamma + x, COALESCED output via LDS bounce.
// grid (qblk2 32, b 4, f 4); each block: 256 q x 32 ch.
// Phase 1: coalesced PACC reads, sum over s, x Linv, stage fp32 in LDS.
// Phase 2: wave w -> 8 ch rows; lane -> q=lane*4: contiguous 1KB load/stores.
// ---------------------------------------------------------------------------
#define MPITCH 268
__global__ __launch_bounds__(256, 4)
void merge4c_kernel(const ushort_t* __restrict__ PACC, const float* __restrict__ PL,
                    const float* __restrict__ x, const float* __restrict__ gamma,
                    float* __restrict__ out) {
  __shared__ float Linv[256];
  __shared__ float ldso[32 * MPITCH];
  const int tid = threadIdx.x;
  const int qblk2 = blockIdx.x, b = blockIdx.y, f = blockIdx.z;
  const int q0 = qblk2 * 256;

  float Ls = 0.f;
#pragma unroll
  for (int s = 0; s < 4; ++s)
    Ls += PL[(size_t)(s * 4 + b) * NPTS + q0 + tid];
  Linv[tid] = gamma[0] / Ls;
  __syncthreads();

  const int ww = tid >> 6, lane = tid & 63, l31 = lane & 31, h = lane >> 5;

#pragma unroll
  for (int g = 0; g < 2; ++g) {
    float acc[16];
#pragma unroll
    for (int r = 0; r < 16; ++r) acc[r] = 0.f;
#pragma unroll
    for (int s = 0; s < 4; ++s) {
      size_t idx = (((((size_t)(s * 4 + b) * 16 + (qblk2 >> 1)) * 8 +
                      (qblk2 & 1) * 4 + ww) * 2 + g) * 4 + f) * 1024 +
                   (size_t)lane * 16;
      bf16x8 a0 = *(const bf16x8*)(PACC + idx);
      bf16x8 a1 = *(const bf16x8*)(PACC + idx + 8);
#pragma unroll
      for (int r = 0; r < 8; ++r) {
        acc[r] += bf2f((ushort_t)a0[r]);
        acc[8 + r] += bf2f((ushort_t)a1[r]);
      }
    }
    const int qb = ww * 64 + g * 32 + 4 * h;
#pragma unroll
    for (int rr = 0; rr < 4; ++rr) {
      int q = qb + 8 * rr;
      f32x4 v;
#pragma unroll
      for (int i = 0; i < 4; ++i) v[i] = acc[rr * 4 + i] * Linv[q + i];
      *(f32x4*)&ldso[l31 * MPITCH + q] = v;  // ch_local = l31
    }
  }
  __syncthreads();

  // phase 2: coalesced: wave ww -> ch rows ww*8..+7, lane -> q = lane*4
  const float* xb = x + ((size_t)b * NCH + f * 32) * NPTS + q0;
  float* ob = out + ((size_t)b * NCH + f * 32) * NPTS + q0;
#pragma unroll
  for (int rr = 0; rr < 8; ++rr) {
    int ch = ww * 8 + rr;
    f32x4 v = *(const f32x4*)&ldso[ch * MPITCH + lane * 4];
    f32x4 xv = *(const f32x4*)(xb + (size_t)ch * NPTS + lane * 4);
    v += xv;
    *(f32x4*)(ob + (size_t)ch * NPTS + lane * 4) = v;
  }
}

// ---------------------------------------------------------------------------
extern "C" void kernel_launch(void* const* d_in, const int* in_sizes, int n_in,
                              void* d_out, int out_size, void* d_ws,
                              size_t ws_size, hipStream_t stream) {
  const float* x     = (const float*)d_in[0];
  const float* xyz   = (const float*)d_in[1];
  const float* Wq    = (const float*)d_in[2];
  const float* bq    = (const float*)d_in[3];
  const float* Wk    = (const float*)d_in[4];
  const float* bk    = (const float*)d_in[5];
  const float* Wv    = (const float*)d_in[6];
  const float* bv    = (const float*)d_in[7];
  const float* gamma = (const float*)d_in[8];
  float* out = (float*)d_out;

  const size_t BN = (size_t)NB * NPTS;
  ushort_t* Qb = (ushort_t*)d_ws;
  ushort_t* Kb = Qb + BN * DQK;
  ushort_t* Vt = Kb + BN * DQK;
  ushort_t* PACC = Vt + BN * NCH;   // 16 bs * 16 qblk * 8 w * 2 g * 4 f * 1024
  float* PL = (float*)(PACC + (size_t)16 * 16 * 8 * 2 * 4 * 1024);
  ushort_t* Wb = (ushort_t*)(PL + 16 * BN / 2);  // 6*8*64*8 = 24576 ushort
  float* bias_pre = (float*)(Wb + 6 * 8 * 64 * 8);

  wprep_kernel<<<6, 512, 0, stream>>>(Wq, bq, Wk, bk, Wv, bv, Wb, bias_pre);
  projm2_kernel<<<dim3(NPTS / 128, NB), 256, 0, stream>>>(
      x, xyz, Wb, bias_pre, Qb, Kb, Vt);
  attn32_kernel<<<256, 512, 0, stream>>>(Qb, Kb, Vt, PACC, PL);
  merge4c_kernel<<<dim3(32, NB, 4), 256, 0, stream>>>(PACC, PL, x, gamma, out);
  (void)in_sizes; (void)n_in; (void)out_size; (void)ws_size;
}